// Round 2
// baseline (273.043 us; speedup 1.0000x reference)
//
#include <hip/hip_runtime.h>
#include <hip/hip_bf16.h>

#define NEXP 64
#define TOPK 8
#define NCAND 10

__global__ __launch_bounds__(256) void topk_router_kernel(
    const float* __restrict__ logits,
    float* __restrict__ w_out,      // [N,8] weights
    float* __restrict__ id_out,     // [N,8] ids stored as float values
    float* __restrict__ l_out,      // [N,64] passthrough copy
    int nrows)
{
    int row = blockIdx.x * blockDim.x + threadIdx.x;
    if (row >= nrows) return;

    const float4* __restrict__ src = (const float4*)(logits + (size_t)row * NEXP);
    float4* __restrict__ dst = (float4*)(l_out + (size_t)row * NEXP);

    // Top-10 candidates by LOGIT, descending, stable (lower index first on
    // exact logit ties): strict > insertion in increasing index order.
    float tv0 = -INFINITY, tv1 = -INFINITY, tv2 = -INFINITY, tv3 = -INFINITY;
    float tv4 = -INFINITY, tv5 = -INFINITY, tv6 = -INFINITY, tv7 = -INFINITY;
    float tv8 = -INFINITY, tv9 = -INFINITY;
    int   ti0 = 0, ti1 = 0, ti2 = 0, ti3 = 0, ti4 = 0;
    int   ti5 = 0, ti6 = 0, ti7 = 0, ti8 = 0, ti9 = 0;

#define INSERT_STAGE(TV, TI)                              \
    {                                                     \
        bool gt = (x > TV);                               \
        float nv = gt ? x  : TV;                          \
        float cv = gt ? TV : x;                           \
        int   ni = gt ? xi : TI;                          \
        int   ci = gt ? TI : xi;                          \
        TV = nv; x = cv; TI = ni; xi = ci;                \
    }

#define INSERT_ELEM(X, XI)                                \
    {                                                     \
        float x = (X); int xi = (XI);                     \
        INSERT_STAGE(tv0, ti0)                            \
        INSERT_STAGE(tv1, ti1)                            \
        INSERT_STAGE(tv2, ti2)                            \
        INSERT_STAGE(tv3, ti3)                            \
        INSERT_STAGE(tv4, ti4)                            \
        INSERT_STAGE(tv5, ti5)                            \
        INSERT_STAGE(tv6, ti6)                            \
        INSERT_STAGE(tv7, ti7)                            \
        INSERT_STAGE(tv8, ti8)                            \
        INSERT_STAGE(tv9, ti9)                            \
    }

    #pragma unroll
    for (int c = 0; c < NEXP / 4; ++c) {
        float4 v = src[c];
        dst[c] = v;                      // passthrough copy from the same regs
        INSERT_ELEM(v.x, c * 4 + 0)
        INSERT_ELEM(v.y, c * 4 + 1)
        INSERT_ELEM(v.z, c * 4 + 2)
        INSERT_ELEM(v.w, c * 4 + 3)
    }

    // fp32 scores via (effectively) correctly-rounded exp: replicate the
    // reference's fp32 score ties (exp collapses near-equal logits).
    float m = tv0;
    float ce0 = (float)exp((double)(tv0 - m));
    float ce1 = (float)exp((double)(tv1 - m));
    float ce2 = (float)exp((double)(tv2 - m));
    float ce3 = (float)exp((double)(tv3 - m));
    float ce4 = (float)exp((double)(tv4 - m));
    float ce5 = (float)exp((double)(tv5 - m));
    float ce6 = (float)exp((double)(tv6 - m));
    float ce7 = (float)exp((double)(tv7 - m));
    float ce8 = (float)exp((double)(tv8 - m));
    float ce9 = (float)exp((double)(tv9 - m));

    // ce is non-increasing (exp monotone on sorted logits); within runs of
    // EQUAL ce, reorder indices ascending (lax.top_k tie-break). Bubble
    // passes; tie runs are tiny (pairs), 4 passes is overkill-safe.
#define TIESWAP(CA, IA, CB, IB)                           \
    {                                                     \
        bool sw = (CA == CB) && (IA > IB);                \
        int t = IA;                                       \
        IA = sw ? IB : IA;                                \
        IB = sw ? t  : IB;                                \
    }
#define TIEPASS                                           \
    TIESWAP(ce0, ti0, ce1, ti1)                           \
    TIESWAP(ce1, ti1, ce2, ti2)                           \
    TIESWAP(ce2, ti2, ce3, ti3)                           \
    TIESWAP(ce3, ti3, ce4, ti4)                           \
    TIESWAP(ce4, ti4, ce5, ti5)                           \
    TIESWAP(ce5, ti5, ce6, ti6)                           \
    TIESWAP(ce6, ti6, ce7, ti7)                           \
    TIESWAP(ce7, ti7, ce8, ti8)                           \
    TIESWAP(ce8, ti8, ce9, ti9)

    TIEPASS
    TIEPASS
    TIEPASS
    TIEPASS

    // Renormalized weights from the selected 8 (full-row denominator cancels).
    float s = ((ce0 + ce1) + (ce2 + ce3)) + ((ce4 + ce5) + (ce6 + ce7));
    float r = 1.0f / s;

    float4 w0 = make_float4(ce0 * r, ce1 * r, ce2 * r, ce3 * r);
    float4 w1 = make_float4(ce4 * r, ce5 * r, ce6 * r, ce7 * r);
    float4 i0 = make_float4((float)ti0, (float)ti1, (float)ti2, (float)ti3);
    float4 i1 = make_float4((float)ti4, (float)ti5, (float)ti6, (float)ti7);

    float4* __restrict__ wp = (float4*)(w_out + (size_t)row * TOPK);
    wp[0] = w0; wp[1] = w1;
    float4* __restrict__ ip = (float4*)(id_out + (size_t)row * TOPK);
    ip[0] = i0; ip[1] = i1;
}

extern "C" void kernel_launch(void* const* d_in, const int* in_sizes, int n_in,
                              void* d_out, int out_size, void* d_ws, size_t ws_size,
                              hipStream_t stream) {
    const float* logits = (const float*)d_in[0];
    int nrows = in_sizes[0] / NEXP;

    float* out   = (float*)d_out;
    float* w_out = out;
    float* id_out = out + (size_t)nrows * TOPK;
    float* l_out  = out + (size_t)nrows * 2 * TOPK;

    int threads = 256;
    int blocks = (nrows + threads - 1) / threads;
    topk_router_kernel<<<blocks, threads, 0, stream>>>(logits, w_out, id_out, l_out, nrows);
}

// Round 3
// 198.867 us; speedup vs baseline: 1.3730x; 1.3730x over previous
//
#include <hip/hip_runtime.h>
#include <hip/hip_bf16.h>

#define NEXP 64
#define TOPK 8
#define ROWS_PER_BLOCK 256
#define CHUNKS 16              // 16 float4 chunks per row

__global__ __launch_bounds__(256) void topk_router_kernel(
    const float* __restrict__ logits,
    float* __restrict__ w_out,      // [N,8] weights
    float* __restrict__ id_out,     // [N,8] ids stored as float values
    float* __restrict__ l_out,      // [N,64] passthrough copy
    int nrows)
{
    // chunk-major LDS tile: tile[c][r], r xor-swizzled by (c&7) so both the
    // staging writes and the per-row reads spread 8 lanes per 4-bank group
    // (the hardware minimum for ds_*_b128 => conflict-free).
    __shared__ float4 tile[CHUNKS * ROWS_PER_BLOCK];   // 64 KB

    const int t = threadIdx.x;
    const size_t blockBase4 = (size_t)blockIdx.x * (ROWS_PER_BLOCK * CHUNKS);
    const size_t totalChunks = (size_t)nrows * CHUNKS;

    const float4* __restrict__ src = (const float4*)logits;
    float4* __restrict__ dst = (float4*)l_out;

    // ---- stage: coalesced global load -> coalesced l_out store + LDS ----
    const int c_st = t & 15;            // chunk this thread stages
    const int rbase = t >> 4;
    #pragma unroll
    for (int s = 0; s < CHUNKS; ++s) {
        size_t g = blockBase4 + (size_t)s * 256 + t;
        if (g < totalChunks) {
            float4 v = src[g];
            dst[g] = v;                                   // passthrough copy
            int r_local = s * 16 + rbase;
            tile[c_st * ROWS_PER_BLOCK + (r_local ^ (c_st & 7))] = v;
        }
    }
    __syncthreads();

    const int row = blockIdx.x * ROWS_PER_BLOCK + t;
    if (row >= nrows) return;

    // ---- prefetch this row's 16 chunks from LDS into registers ----
    float4 d[CHUNKS];
    #pragma unroll
    for (int c = 0; c < CHUNKS; ++c)
        d[c] = tile[c * ROWS_PER_BLOCK + (t ^ (c & 7))];

    // ---- top-10 by logit, descending, stable (strict >, increasing idx) ----
    float tv0 = -INFINITY, tv1 = -INFINITY, tv2 = -INFINITY, tv3 = -INFINITY;
    float tv4 = -INFINITY, tv5 = -INFINITY, tv6 = -INFINITY, tv7 = -INFINITY;
    float tv8 = -INFINITY, tv9 = -INFINITY;
    int   ti0 = 0, ti1 = 0, ti2 = 0, ti3 = 0, ti4 = 0;
    int   ti5 = 0, ti6 = 0, ti7 = 0, ti8 = 0, ti9 = 0;

#define INSERT_STAGE(TV, TI)                              \
    {                                                     \
        bool gt = (x > TV);                               \
        float nv = gt ? x  : TV;                          \
        float cv = gt ? TV : x;                           \
        int   ni = gt ? xi : TI;                          \
        int   ci = gt ? TI : xi;                          \
        TV = nv; x = cv; TI = ni; xi = ci;                \
    }

#define INSERT_ELEM(X, XI)                                \
    {                                                     \
        float x = (X); int xi = (XI);                     \
        INSERT_STAGE(tv0, ti0)                            \
        INSERT_STAGE(tv1, ti1)                            \
        INSERT_STAGE(tv2, ti2)                            \
        INSERT_STAGE(tv3, ti3)                            \
        INSERT_STAGE(tv4, ti4)                            \
        INSERT_STAGE(tv5, ti5)                            \
        INSERT_STAGE(tv6, ti6)                            \
        INSERT_STAGE(tv7, ti7)                            \
        INSERT_STAGE(tv8, ti8)                            \
        INSERT_STAGE(tv9, ti9)                            \
    }

    #pragma unroll
    for (int c = 0; c < CHUNKS; ++c) {
        INSERT_ELEM(d[c].x, c * 4 + 0)
        INSERT_ELEM(d[c].y, c * 4 + 1)
        INSERT_ELEM(d[c].z, c * 4 + 2)
        INSERT_ELEM(d[c].w, c * 4 + 3)
    }

    // ---- tie screen: fp32 exp collapses only when adjacent logit gap
    // < ~1.2e-7; trigger the exact path at 1e-6 (8x safety margin). ----
    const float T = 1e-6f;
    bool tie = ((tv0 - tv1) <= T) | ((tv1 - tv2) <= T) | ((tv2 - tv3) <= T) |
               ((tv3 - tv4) <= T) | ((tv4 - tv5) <= T) | ((tv5 - tv6) <= T) |
               ((tv6 - tv7) <= T) | ((tv7 - tv8) <= T) | ((tv8 - tv9) <= T);

    float ce0, ce1, ce2, ce3, ce4, ce5, ce6, ce7;
    int   o0, o1, o2, o3, o4, o5, o6, o7;

    if (!tie) {
        // fast path: no representable tie possible; __expf is plenty accurate
        ce0 = 1.0f;
        ce1 = __expf(tv1 - tv0); ce2 = __expf(tv2 - tv0);
        ce3 = __expf(tv3 - tv0); ce4 = __expf(tv4 - tv0);
        ce5 = __expf(tv5 - tv0); ce6 = __expf(tv6 - tv0);
        ce7 = __expf(tv7 - tv0);
        o0 = ti0; o1 = ti1; o2 = ti2; o3 = ti3;
        o4 = ti4; o5 = ti5; o6 = ti6; o7 = ti7;
    } else {
        // exact path: replicate reference fp32-score ties (correctly-rounded
        // exp), then ascending-index within equal-score runs (lax.top_k).
        double m = (double)tv0;
        float s0 = (float)exp((double)tv0 - m);
        float s1 = (float)exp((double)tv1 - m);
        float s2 = (float)exp((double)tv2 - m);
        float s3 = (float)exp((double)tv3 - m);
        float s4 = (float)exp((double)tv4 - m);
        float s5 = (float)exp((double)tv5 - m);
        float s6 = (float)exp((double)tv6 - m);
        float s7 = (float)exp((double)tv7 - m);
        float s8 = (float)exp((double)tv8 - m);
        float s9 = (float)exp((double)tv9 - m);

#define TIESWAP(CA, IA, CB, IB)                           \
    {                                                     \
        bool sw = (CA == CB) && (IA > IB);                \
        int tt = IA;                                      \
        IA = sw ? IB : IA;                                \
        IB = sw ? tt : IB;                                \
    }
#define TIEPASS                                           \
    TIESWAP(s0, ti0, s1, ti1)                             \
    TIESWAP(s1, ti1, s2, ti2)                             \
    TIESWAP(s2, ti2, s3, ti3)                             \
    TIESWAP(s3, ti3, s4, ti4)                             \
    TIESWAP(s4, ti4, s5, ti5)                             \
    TIESWAP(s5, ti5, s6, ti6)                             \
    TIESWAP(s6, ti6, s7, ti7)                             \
    TIESWAP(s7, ti7, s8, ti8)                             \
    TIESWAP(s8, ti8, s9, ti9)

        TIEPASS
        TIEPASS
        TIEPASS
        TIEPASS

        ce0 = s0; ce1 = s1; ce2 = s2; ce3 = s3;
        ce4 = s4; ce5 = s5; ce6 = s6; ce7 = s7;
        o0 = ti0; o1 = ti1; o2 = ti2; o3 = ti3;
        o4 = ti4; o5 = ti5; o6 = ti6; o7 = ti7;
    }

    float s = ((ce0 + ce1) + (ce2 + ce3)) + ((ce4 + ce5) + (ce6 + ce7));
    float r = 1.0f / s;

    float4 w0 = make_float4(ce0 * r, ce1 * r, ce2 * r, ce3 * r);
    float4 w1 = make_float4(ce4 * r, ce5 * r, ce6 * r, ce7 * r);
    float4 i0 = make_float4((float)o0, (float)o1, (float)o2, (float)o3);
    float4 i1 = make_float4((float)o4, (float)o5, (float)o6, (float)o7);

    float4* __restrict__ wp = (float4*)(w_out + (size_t)row * TOPK);
    wp[0] = w0; wp[1] = w1;
    float4* __restrict__ ip = (float4*)(id_out + (size_t)row * TOPK);
    ip[0] = i0; ip[1] = i1;
}

extern "C" void kernel_launch(void* const* d_in, const int* in_sizes, int n_in,
                              void* d_out, int out_size, void* d_ws, size_t ws_size,
                              hipStream_t stream) {
    const float* logits = (const float*)d_in[0];
    int nrows = in_sizes[0] / NEXP;

    float* out    = (float*)d_out;
    float* w_out  = out;
    float* id_out = out + (size_t)nrows * TOPK;
    float* l_out  = out + (size_t)nrows * 2 * TOPK;

    int threads = 256;
    int blocks = (nrows + ROWS_PER_BLOCK - 1) / ROWS_PER_BLOCK;
    topk_router_kernel<<<blocks, threads, 0, stream>>>(logits, w_out, id_out, l_out, nrows);
}

// Round 4
// 161.695 us; speedup vs baseline: 1.6886x; 1.2299x over previous
//
#include <hip/hip_runtime.h>
#include <hip/hip_bf16.h>

#define NEXP 64
#define TOPK 8
#define RPB 256                 // rows per block
#define HCH 8                   // chunks per phase (half of 16)

__global__ __launch_bounds__(256) void topk_router_kernel(
    const float* __restrict__ logits,
    float* __restrict__ w_out,      // [N,8] weights
    float* __restrict__ id_out,     // [N,8] ids stored as float values
    float* __restrict__ l_out,      // [N,64] passthrough copy
    int nrows)
{
    // Half-row tile, reused for both phases: tile[c][r ^ c], c in 0..7.
    // Writes: 8 lanes per 4-bank group with distinct 16B slots = b128 hw
    // minimum (measured 0 conflicts in the previous round). Reads: row t's
    // chunks are a permutation of consecutive slots = conflict-free.
    __shared__ float4 tile[HCH * RPB];   // 32 KB

    const int t = threadIdx.x;
    const size_t blockBase4 = (size_t)blockIdx.x * (RPB * 16);
    const size_t totalChunks = (size_t)nrows * 16;

    const float4* __restrict__ src = (const float4*)logits;
    float4* __restrict__ dst = (float4*)l_out;

    // ---- phase A stage: chunks 0..7 of all 256 rows ----
    #pragma unroll
    for (int i = 0; i < 8; ++i) {
        int j = i * 256 + t;
        int r = j >> 3, c = j & 7;
        size_t g = blockBase4 + (size_t)r * 16 + c;
        if (g < totalChunks) {
            float4 v = src[g];
            dst[g] = v;                         // passthrough copy
            tile[c * RPB + (r ^ c)] = v;
        }
    }

    // ---- issue phase-B global loads now (in flight across barrier+compute) ----
    float4 vb[8];
    #pragma unroll
    for (int i = 0; i < 8; ++i) {
        int j = i * 256 + t;
        int r = j >> 3, c = j & 7;
        size_t g = blockBase4 + (size_t)r * 16 + 8 + c;
        vb[i] = (g < totalChunks) ? src[g] : make_float4(0.f, 0.f, 0.f, 0.f);
    }

    __syncthreads();

    const int row = blockIdx.x * RPB + t;
    const bool active = (row < nrows);

    // ---- read my row's chunks 0..7 ----
    float4 d0 = tile[0 * RPB + (t ^ 0)];
    float4 d1 = tile[1 * RPB + (t ^ 1)];
    float4 d2 = tile[2 * RPB + (t ^ 2)];
    float4 d3 = tile[3 * RPB + (t ^ 3)];
    float4 d4 = tile[4 * RPB + (t ^ 4)];
    float4 d5 = tile[5 * RPB + (t ^ 5)];
    float4 d6 = tile[6 * RPB + (t ^ 6)];
    float4 d7 = tile[7 * RPB + (t ^ 7)];

    // ---- top-10 by logit, descending, stable (strict >, increasing idx) ----
    float tv0 = -INFINITY, tv1 = -INFINITY, tv2 = -INFINITY, tv3 = -INFINITY;
    float tv4 = -INFINITY, tv5 = -INFINITY, tv6 = -INFINITY, tv7 = -INFINITY;
    float tv8 = -INFINITY, tv9 = -INFINITY;
    int   ti0 = 0, ti1 = 0, ti2 = 0, ti3 = 0, ti4 = 0;
    int   ti5 = 0, ti6 = 0, ti7 = 0, ti8 = 0, ti9 = 0;

#define INSERT_STAGE(TV, TI)                              \
    {                                                     \
        bool gt = (x > TV);                               \
        float nv = gt ? x  : TV;                          \
        float cv = gt ? TV : x;                           \
        int   ni = gt ? xi : TI;                          \
        int   ci = gt ? TI : xi;                          \
        TV = nv; x = cv; TI = ni; xi = ci;                \
    }

#define INSERT_ELEM(X, XI)                                \
    {                                                     \
        float x = (X); int xi = (XI);                     \
        INSERT_STAGE(tv0, ti0)                            \
        INSERT_STAGE(tv1, ti1)                            \
        INSERT_STAGE(tv2, ti2)                            \
        INSERT_STAGE(tv3, ti3)                            \
        INSERT_STAGE(tv4, ti4)                            \
        INSERT_STAGE(tv5, ti5)                            \
        INSERT_STAGE(tv6, ti6)                            \
        INSERT_STAGE(tv7, ti7)                            \
        INSERT_STAGE(tv8, ti8)                            \
        INSERT_STAGE(tv9, ti9)                            \
    }

#define INSERT_CHUNK(D, CI)                               \
    INSERT_ELEM((D).x, (CI) * 4 + 0)                      \
    INSERT_ELEM((D).y, (CI) * 4 + 1)                      \
    INSERT_ELEM((D).z, (CI) * 4 + 2)                      \
    INSERT_ELEM((D).w, (CI) * 4 + 3)

    // process chunks 0..7 (indices 0..31) while phase-B loads are in flight
    INSERT_CHUNK(d0, 0)
    INSERT_CHUNK(d1, 1)
    INSERT_CHUNK(d2, 2)
    INSERT_CHUNK(d3, 3)
    INSERT_CHUNK(d4, 4)
    INSERT_CHUNK(d5, 5)
    INSERT_CHUNK(d6, 6)
    INSERT_CHUNK(d7, 7)

    __syncthreads();   // everyone done reading tile (reads consumed above)

    // ---- phase B stage: chunks 8..15 into the same tile ----
    #pragma unroll
    for (int i = 0; i < 8; ++i) {
        int j = i * 256 + t;
        int r = j >> 3, c = j & 7;
        size_t g = blockBase4 + (size_t)r * 16 + 8 + c;
        if (g < totalChunks) dst[g] = vb[i];    // passthrough copy
        tile[c * RPB + (r ^ c)] = vb[i];
    }

    __syncthreads();

    d0 = tile[0 * RPB + (t ^ 0)];
    d1 = tile[1 * RPB + (t ^ 1)];
    d2 = tile[2 * RPB + (t ^ 2)];
    d3 = tile[3 * RPB + (t ^ 3)];
    d4 = tile[4 * RPB + (t ^ 4)];
    d5 = tile[5 * RPB + (t ^ 5)];
    d6 = tile[6 * RPB + (t ^ 6)];
    d7 = tile[7 * RPB + (t ^ 7)];

    // chunks 8..15 (indices 32..63)
    INSERT_CHUNK(d0, 8)
    INSERT_CHUNK(d1, 9)
    INSERT_CHUNK(d2, 10)
    INSERT_CHUNK(d3, 11)
    INSERT_CHUNK(d4, 12)
    INSERT_CHUNK(d5, 13)
    INSERT_CHUNK(d6, 14)
    INSERT_CHUNK(d7, 15)

    if (!active) return;

    // ---- tie screen: fp32 exp collapses only when adjacent logit gap
    // < ~1.2e-7; trigger the exact path at 1e-6 (8x safety margin). ----
    const float T = 1e-6f;
    bool tie = ((tv0 - tv1) <= T) | ((tv1 - tv2) <= T) | ((tv2 - tv3) <= T) |
               ((tv3 - tv4) <= T) | ((tv4 - tv5) <= T) | ((tv5 - tv6) <= T) |
               ((tv6 - tv7) <= T) | ((tv7 - tv8) <= T) | ((tv8 - tv9) <= T);

    float ce0, ce1, ce2, ce3, ce4, ce5, ce6, ce7;
    int   o0, o1, o2, o3, o4, o5, o6, o7;

    if (!tie) {
        ce0 = 1.0f;
        ce1 = __expf(tv1 - tv0); ce2 = __expf(tv2 - tv0);
        ce3 = __expf(tv3 - tv0); ce4 = __expf(tv4 - tv0);
        ce5 = __expf(tv5 - tv0); ce6 = __expf(tv6 - tv0);
        ce7 = __expf(tv7 - tv0);
        o0 = ti0; o1 = ti1; o2 = ti2; o3 = ti3;
        o4 = ti4; o5 = ti5; o6 = ti6; o7 = ti7;
    } else {
        // exact path: replicate reference fp32-score ties (correctly-rounded
        // exp), then ascending-index within equal-score runs (lax.top_k).
        double m = (double)tv0;
        float s0 = (float)exp((double)tv0 - m);
        float s1 = (float)exp((double)tv1 - m);
        float s2 = (float)exp((double)tv2 - m);
        float s3 = (float)exp((double)tv3 - m);
        float s4 = (float)exp((double)tv4 - m);
        float s5 = (float)exp((double)tv5 - m);
        float s6 = (float)exp((double)tv6 - m);
        float s7 = (float)exp((double)tv7 - m);
        float s8 = (float)exp((double)tv8 - m);
        float s9 = (float)exp((double)tv9 - m);

#define TIESWAP(CA, IA, CB, IB)                           \
    {                                                     \
        bool sw = (CA == CB) && (IA > IB);                \
        int tt = IA;                                      \
        IA = sw ? IB : IA;                                \
        IB = sw ? tt : IB;                                \
    }
#define TIEPASS                                           \
    TIESWAP(s0, ti0, s1, ti1)                             \
    TIESWAP(s1, ti1, s2, ti2)                             \
    TIESWAP(s2, ti2, s3, ti3)                             \
    TIESWAP(s3, ti3, s4, ti4)                             \
    TIESWAP(s4, ti4, s5, ti5)                             \
    TIESWAP(s5, ti5, s6, ti6)                             \
    TIESWAP(s6, ti6, s7, ti7)                             \
    TIESWAP(s7, ti7, s8, ti8)                             \
    TIESWAP(s8, ti8, s9, ti9)

        TIEPASS
        TIEPASS
        TIEPASS
        TIEPASS

        ce0 = s0; ce1 = s1; ce2 = s2; ce3 = s3;
        ce4 = s4; ce5 = s5; ce6 = s6; ce7 = s7;
        o0 = ti0; o1 = ti1; o2 = ti2; o3 = ti3;
        o4 = ti4; o5 = ti5; o6 = ti6; o7 = ti7;
    }

    float s = ((ce0 + ce1) + (ce2 + ce3)) + ((ce4 + ce5) + (ce6 + ce7));
    float r = 1.0f / s;

    float4 w0 = make_float4(ce0 * r, ce1 * r, ce2 * r, ce3 * r);
    float4 w1 = make_float4(ce4 * r, ce5 * r, ce6 * r, ce7 * r);
    float4 i0 = make_float4((float)o0, (float)o1, (float)o2, (float)o3);
    float4 i1 = make_float4((float)o4, (float)o5, (float)o6, (float)o7);

    float4* __restrict__ wp = (float4*)(w_out + (size_t)row * TOPK);
    wp[0] = w0; wp[1] = w1;
    float4* __restrict__ ip = (float4*)(id_out + (size_t)row * TOPK);
    ip[0] = i0; ip[1] = i1;
}

extern "C" void kernel_launch(void* const* d_in, const int* in_sizes, int n_in,
                              void* d_out, int out_size, void* d_ws, size_t ws_size,
                              hipStream_t stream) {
    const float* logits = (const float*)d_in[0];
    int nrows = in_sizes[0] / NEXP;

    float* out    = (float*)d_out;
    float* w_out  = out;
    float* id_out = out + (size_t)nrows * TOPK;
    float* l_out  = out + (size_t)nrows * 2 * TOPK;

    int threads = 256;
    int blocks = (nrows + RPB - 1) / RPB;
    topk_router_kernel<<<blocks, threads, 0, stream>>>(logits, w_out, id_out, l_out, nrows);
}